// Round 5
// baseline (1071.880 us; speedup 1.0000x reference)
//
#include <hip/hip_runtime.h>
#include <hip/hip_bf16.h>
#include <stdint.h>

typedef __attribute__((ext_vector_type(8))) __bf16 bf16x8;
typedef __attribute__((ext_vector_type(4))) float f32x4;
typedef __attribute__((ext_vector_type(16))) float f32x16;

static constexpr int kTokens = 8192;   // B*S = 4*2048
static constexpr int kHid    = 2048;   // H
static constexpr int kInter  = 8192;   // I
static constexpr int kN1     = 16384;  // 2*I, branch-interleaved in 32-col groups

// ---------------- async global->LDS 16B copy (global_load_lds_dwordx4) ----
__device__ __forceinline__ void async16(const void* g, void* l) {
  using gp = const __attribute__((address_space(1))) unsigned int*;
  using lp = __attribute__((address_space(3))) unsigned int*;
  __builtin_amdgcn_global_load_lds((gp)(uintptr_t)g,
                                   (lp)(unsigned int)(uintptr_t)l, 16, 0, 0);
}

// ---------------- LayerNorm (f32 in) -> bf16 y --------------------------
__global__ __launch_bounds__(256) void ln_kernel(
    const float* __restrict__ x, const float* __restrict__ gamma,
    const float* __restrict__ beta, __hip_bfloat16* __restrict__ y) {
  const int t = threadIdx.x;
  const size_t row = blockIdx.x;
  const float* xr = x + row * kHid;
  float4 v0 = ((const float4*)xr)[2 * t];
  float4 v1 = ((const float4*)xr)[2 * t + 1];
  float s  = v0.x + v0.y + v0.z + v0.w + v1.x + v1.y + v1.z + v1.w;
  float s2 = v0.x*v0.x + v0.y*v0.y + v0.z*v0.z + v0.w*v0.w
           + v1.x*v1.x + v1.y*v1.y + v1.z*v1.z + v1.w*v1.w;
#pragma unroll
  for (int off = 1; off < 64; off <<= 1) {
    s  += __shfl_xor(s, off, 64);
    s2 += __shfl_xor(s2, off, 64);
  }
  __shared__ float red[8];
  const int w = t >> 6;
  if ((t & 63) == 0) { red[w] = s; red[4 + w] = s2; }
  __syncthreads();
  s  = red[0] + red[1] + red[2] + red[3];
  s2 = red[4] + red[5] + red[6] + red[7];
  const float mu = s * (1.0f / kHid);
  const float rs = rsqrtf(s2 * (1.0f / kHid) - mu * mu + 1e-6f);
  float4 g0 = ((const float4*)gamma)[2 * t], g1 = ((const float4*)gamma)[2 * t + 1];
  float4 b0 = ((const float4*)beta)[2 * t],  b1 = ((const float4*)beta)[2 * t + 1];
  union { __hip_bfloat16 h[8]; uint4 u; } pk;
  pk.h[0] = __float2bfloat16((v0.x - mu) * rs * g0.x + b0.x);
  pk.h[1] = __float2bfloat16((v0.y - mu) * rs * g0.y + b0.y);
  pk.h[2] = __float2bfloat16((v0.z - mu) * rs * g0.z + b0.z);
  pk.h[3] = __float2bfloat16((v0.w - mu) * rs * g0.w + b0.w);
  pk.h[4] = __float2bfloat16((v1.x - mu) * rs * g1.x + b1.x);
  pk.h[5] = __float2bfloat16((v1.y - mu) * rs * g1.y + b1.y);
  pk.h[6] = __float2bfloat16((v1.z - mu) * rs * g1.z + b1.z);
  pk.h[7] = __float2bfloat16((v1.w - mu) * rs * g1.w + b1.w);
  ((uint4*)(y + row * kHid))[t] = pk.u;
}

// ---------------- f32 (K x Ncols) -> bf16 transposed (N x K) -------------
// INTERLEAVE=true: 32-col gate/linear groups (matches 32x32 MFMA N-tiles):
// dst row n -> src col a*8192 + i, a = (n>>5)&1, i = ((n>>6)<<5)|(n&31).
template <bool INTERLEAVE>
__global__ __launch_bounds__(256) void cvt_tr(
    const float* __restrict__ src, __hip_bfloat16* __restrict__ dst,
    int K, int N) {
  __shared__ float tile[64][65];
  const int nb = blockIdx.x * 64;
  const int kb = blockIdx.y * 64;
  const int t = threadIdx.x;
#pragma unroll
  for (int it = 0; it < 16; ++it) {
    int p = t + it * 256;
    int lk = p >> 6, ln = p & 63;
    int n = nb + ln;
    int col = INTERLEAVE ? ((((n >> 5) & 1) << 13) + (((n >> 6) << 5) | (n & 31)))
                         : n;
    tile[lk][ln] = src[(size_t)(kb + lk) * N + col];
  }
  __syncthreads();
#pragma unroll
  for (int it = 0; it < 16; ++it) {
    int p = t + it * 256;
    int ln = p >> 6, lk = p & 63;
    dst[(size_t)(nb + ln) * K + kb + lk] = __float2bfloat16(tile[lk][ln]);
  }
}

// ---------------- 256x256 8-phase bf16 GEMM  C = A(MxK) * B^T(NxK) -------
// R4: MFMA shape 16x16x32 -> 32x32x16 (u-bench ceiling 2495 vs 2176 TF;
// 4x fewer MFMA instructions; frag VGPRs 64 -> 48). Skeleton unchanged:
// BK=64, 8 waves (2Mx4N), wave tile 128x64 = 4x2 tiles of 32x32,
// 2x64KB LDS dbuf + dummy sink, chunk-XOR swizzle (chunk ^= row&7),
// vmcnt(4) at ph4/ph8, R0 staging ledger:
//   ph1:(2i+1).A0 ph2:(2i+1).A1 ph3:(2i+2).B0 ph4:(2i+2).B1+VM
//   ph5:(2i+2).A0 ph6:(2i+2).A1 ph7:(2i+3).B0 ph8:(2i+3).B1+VM
// Per-phase reads 8/8/4/4 (A m-pair x k-pair; B full-K read ph1/ph2 so the
// B slot's last read precedes its ph3 restage by >=1 barrier pair).
// A/B frag (32x32x16): row/col = lane&31, k = (lane>>5)*8 + e; per-lane
// ds addr precomputed per {buf, ksub}; mt/nt*4096 folded as imm offset.
// Bank check: chunk = ((ks*2)|hi)^(lane&7): each chunk-col hit by 8 lanes
// -> 8 dword-accesses/bank = wave64-b128 minimum, conflict-free.
// C/D: col = lane&31, row = (reg&3)+8*(reg>>2)+4*(lane>>5)  [m74/m101].
#define SLOT_A(b, h) ((b) * 65536 + (h) * 16384)
#define SLOT_B(b, h) ((b) * 65536 + 32768 + (h) * 16384)
#define SLOT_DUMMY 131072

template <int EPI, int NXTLOG>
__global__ __launch_bounds__(512, 2) void gemm8p(
    const __hip_bfloat16* __restrict__ A, const __hip_bfloat16* __restrict__ B,
    void* __restrict__ Cout, int M, int N, int K) {
  __shared__ __align__(16) char smem[139264];
  char* const sm = (char*)smem;

  const int t = threadIdx.x;
  const int lane = t & 63;
  const int wave = t >> 6;
  const int wm = wave >> 2;  // 0..1 (M waves, 128 rows each)
  const int wn = wave & 3;   // 0..3 (N waves, 64 cols each)

  // XCD-aware bijective swizzle (caller guarantees grid % 8 == 0)
  const int nwg = (int)gridDim.x;
  const int wg = ((int)blockIdx.x & 7) * (nwg >> 3) + ((int)blockIdx.x >> 3);
  const int bx = wg & ((1 << NXTLOG) - 1);
  const int by = wg >> NXTLOG;
  const size_t m0 = (size_t)by * 256;
  const size_t n0 = (size_t)bx * 256;

  // staging lane constants: thread t writes linear LDS bytes t*16 (+8192);
  // row = t>>3 (+64 for 2nd load), stored chunk = t&7, source chunk XOR'd.
  const int srow = t >> 3;
  const int scsrc = (t & 7) ^ (srow & 7);
  const __hip_bfloat16* const gA = A + (m0 + srow) * K + scsrc * 8;
  const __hip_bfloat16* const gB = B + (n0 + srow) * K + scsrc * 8;
  const size_t K64  = (size_t)64 * K;
  const size_t K128 = (size_t)128 * K;
  const int t16 = t * 16;
  char* const dm = sm + SLOT_DUMMY + t16;

  // fragment-read lane constants (32x32x16): row/col = lane&31,
  // k-half by hi = lane>>5; logical chunk (ks*2)|hi, stored ^ (lane&7).
  const int l31 = lane & 31, hi = lane >> 5, l7 = lane & 7;
  int aAdr[2][4], bAdr[2][4];
#pragma unroll
  for (int b2 = 0; b2 < 2; ++b2)
#pragma unroll
    for (int ks = 0; ks < 4; ++ks) {
      const int ch = (((ks << 1) | hi) ^ l7) << 4;
      aAdr[b2][ks] = b2 * 65536 + (((wm << 7) + l31) << 7) + ch;
      bAdr[b2][ks] = b2 * 65536 + 32768 + (((wn << 6) + l31) << 7) + ch;
    }

  f32x16 acc[4][2] = {};      // [mt][nt]
  bf16x8 a[2][2];             // current m-pair x k-pair
  bf16x8 b0[2][2], b1[2][2];  // [nt][kk] for k-pair 0 / 1

  const int NT = K >> 6;  // 64-wide K tiles (even for both GEMMs)
  const int L  = NT >> 1; // 2 tiles per iteration

#define STG_A(tile, h, buf)                                           \
  do {                                                                \
    const __hip_bfloat16* _s = gA + (size_t)(tile) * 64 + (h) * K128; \
    char* _d = sm + SLOT_A(buf, h) + t16;                             \
    async16(_s, _d);                                                  \
    async16(_s + K64, _d + 8192);                                     \
  } while (0)
#define STG_B(tile, h, buf)                                           \
  do {                                                                \
    const __hip_bfloat16* _s = gB + (size_t)(tile) * 64 + (h) * K128; \
    char* _d = sm + SLOT_B(buf, h) + t16;                             \
    async16(_s, _d);                                                  \
    async16(_s + K64, _d + 8192);                                     \
  } while (0)
#define STG_A_G(tile, h, buf)                  \
  do {                                         \
    if ((tile) < NT) { STG_A(tile, h, buf); }  \
    else { async16(A, dm); async16(A, dm); }   \
  } while (0)
#define STG_B_G(tile, h, buf)                  \
  do {                                         \
    if ((tile) < NT) { STG_B(tile, h, buf); }  \
    else { async16(A, dm); async16(A, dm); }   \
  } while (0)

  // a[m][kk] <- A frag (m-tile mt, k-sub ks) from buf
#define RD_A(buf, m, mt, ks, kk) \
  a[m][kk] = *(const bf16x8*)(sm + aAdr[buf][ks] + (mt) * 4096);
  // B[nt][kk] <- B frag (n-tile nt, k-sub ks) from buf
#define RD_B(buf, dst, nt, ks, kk) \
  dst[nt][kk] = *(const bf16x8*)(sm + bAdr[buf][ks] + (nt) * 4096);

  // load A m-pair {mb, mb+1} x k-pair kp from buf
#define LOAD_A4(buf, mb, kp)            \
  RD_A(buf, 0, mb,     (kp)*2,     0)   \
  RD_A(buf, 0, mb,     (kp)*2 + 1, 1)   \
  RD_A(buf, 1, (mb)+1, (kp)*2,     0)   \
  RD_A(buf, 1, (mb)+1, (kp)*2 + 1, 1)
  // load B both n-tiles x k-pair kp into dst
#define LOAD_B4(buf, dst, kp)           \
  RD_B(buf, dst, 0, (kp)*2,     0)      \
  RD_B(buf, dst, 0, (kp)*2 + 1, 1)      \
  RD_B(buf, dst, 1, (kp)*2,     0)      \
  RD_B(buf, dst, 1, (kp)*2 + 1, 1)

  // 8 MFMAs: acc[mb..mb+1][0..1] += a x Bp (both kk)
#define MFMA8(mb, Bp)                                                       \
  { _Pragma("unroll") for (int kk = 0; kk < 2; ++kk)                        \
    _Pragma("unroll") for (int m = 0; m < 2; ++m)                           \
    _Pragma("unroll") for (int nt = 0; nt < 2; ++nt)                        \
      acc[(mb) + m][nt] = __builtin_amdgcn_mfma_f32_32x32x16_bf16(          \
          a[m][kk], Bp[nt][kk], acc[(mb) + m][nt], 0, 0, 0); }

#define PHASE_MID()                                  \
  __builtin_amdgcn_s_barrier();                      \
  asm volatile("s_waitcnt lgkmcnt(0)" ::: "memory"); \
  __builtin_amdgcn_s_setprio(1)
#define PHASE_MID_VM()                               \
  asm volatile("s_waitcnt vmcnt(4)" ::: "memory");   \
  __builtin_amdgcn_s_barrier();                      \
  asm volatile("s_waitcnt lgkmcnt(0)" ::: "memory"); \
  __builtin_amdgcn_s_setprio(1)
#define PHASE_END()                                  \
  __builtin_amdgcn_s_setprio(0);                     \
  __builtin_amdgcn_s_barrier()

  // prologue: tile0 {A,B} -> buf0, tile1 {B} -> buf1; vmcnt(4) leaves
  // tile1.B in flight (steady-state ledger).
  STG_A(0, 0, 0);
  STG_A(0, 1, 0);
  STG_B(0, 0, 0);
  STG_B(0, 1, 0);
  STG_B(1, 0, 1);
  STG_B(1, 1, 1);
  asm volatile("s_waitcnt vmcnt(4)" ::: "memory");
  __builtin_amdgcn_s_barrier();

#pragma unroll 1
  for (int i = 0; i < L; ++i) {
    const int t1 = 2 * i + 1, t2 = 2 * i + 2, t3 = 2 * i + 3;
    // ph1 (buf0): A m01 kp0 + B kp0; mfma m01 x b0
    LOAD_A4(0, 0, 0)
    LOAD_B4(0, b0, 0)
    STG_A(t1, 0, 1);
    PHASE_MID(); MFMA8(0, b0) PHASE_END();
    // ph2: A m23 kp0 + B kp1 (B slot's last read); mfma m23 x b0
    LOAD_A4(0, 2, 0)
    LOAD_B4(0, b1, 1)
    STG_A(t1, 1, 1);
    PHASE_MID(); MFMA8(2, b0) PHASE_END();
    // ph3: A m01 kp1; stage t2.B0 (slot free since ph2); mfma m01 x b1
    LOAD_A4(0, 0, 1)
    STG_B_G(t2, 0, 0);
    PHASE_MID(); MFMA8(0, b1) PHASE_END();
    // ph4: A m23 kp1; stage t2.B1; vmcnt(4) -> tile1 {A,B} resident
    LOAD_A4(0, 2, 1)
    STG_B_G(t2, 1, 0);
    PHASE_MID_VM(); MFMA8(2, b1) PHASE_END();
    // ph5 (buf1): A m01 kp0 + B kp0; stage t2.A0 (A slot free since ph4)
    LOAD_A4(1, 0, 0)
    LOAD_B4(1, b0, 0)
    STG_A_G(t2, 0, 0);
    PHASE_MID(); MFMA8(0, b0) PHASE_END();
    // ph6: A m23 kp0 + B kp1; stage t2.A1
    LOAD_A4(1, 2, 0)
    LOAD_B4(1, b1, 1)
    STG_A_G(t2, 1, 0);
    PHASE_MID(); MFMA8(2, b0) PHASE_END();
    // ph7: A m01 kp1; stage t3.B0
    LOAD_A4(1, 0, 1)
    STG_B_G(t3, 0, 1);
    PHASE_MID(); MFMA8(0, b1) PHASE_END();
    // ph8: A m23 kp1; stage t3.B1; vmcnt(4) -> tile2 {A,B} resident
    LOAD_A4(1, 2, 1)
    STG_B_G(t3, 1, 1);
    PHASE_MID_VM(); MFMA8(2, b1) PHASE_END();
  }
  asm volatile("s_waitcnt vmcnt(0)" ::: "memory");  // drain before LDS dealloc

  // C/D (32x32): col = lane&31, row = (reg&3) + 8*(reg>>2) + 4*hi
  const int gr0 = (int)m0 + wm * 128 + 4 * hi;
  if (EPI == 0) {
    float* Cf = (float*)Cout;
    const int gc0 = (int)n0 + wn * 64 + l31;
#pragma unroll
    for (int mt = 0; mt < 4; ++mt)
#pragma unroll
      for (int nt = 0; nt < 2; ++nt)
#pragma unroll
        for (int g4 = 0; g4 < 4; ++g4)
#pragma unroll
          for (int r = 0; r < 4; ++r)
            Cf[(size_t)(gr0 + mt * 32 + g4 * 8 + r) * N + gc0 + nt * 32] =
                acc[mt][nt][g4 * 4 + r];
  } else {
    __hip_bfloat16* Z = (__hip_bfloat16*)Cout;
    const int ldz = N >> 1;
    // wave covers 64 N-cols = one 32-col gate tile (nt=0) + linear (nt=1);
    // intermediate col = (n0 + wn*64)/2 + (lane&31), same lane both tiles.
    const size_t zc = (n0 >> 1) + wn * 32 + l31;
#pragma unroll
    for (int mt = 0; mt < 4; ++mt)
#pragma unroll
      for (int g4 = 0; g4 < 4; ++g4)
#pragma unroll
        for (int r = 0; r < 4; ++r) {
          const float xv = acc[mt][0][g4 * 4 + r];   // gate
          const float lv = acc[mt][1][g4 * 4 + r];   // linear
          // gelu_tanh(x) = x * sigmoid(2u), u = 0.79788456*(x + 0.044715 x^3)
          float u = 0.7978845608028654f * xv * (1.0f + 0.044715f * xv * xv);
          float sg = __builtin_amdgcn_rcpf(1.0f + __expf(-2.0f * u));
          Z[(size_t)(gr0 + mt * 32 + g4 * 8 + r) * ldz + zc] =
              __float2bfloat16(xv * sg * lv);
        }
  }
}

extern "C" void kernel_launch(void* const* d_in, const int* in_sizes, int n_in,
                              void* d_out, int out_size, void* d_ws, size_t ws_size,
                              hipStream_t stream) {
  const float* x     = (const float*)d_in[0];
  const float* gamma = (const float*)d_in[1];
  const float* beta  = (const float*)d_in[2];
  const float* W1    = (const float*)d_in[3];  // [H, 2, I] f32
  const float* W2    = (const float*)d_in[4];  // [I, H] f32
  float* out = (float*)d_out;

  char* ws = (char*)d_ws;
  __hip_bfloat16* yb  = (__hip_bfloat16*)ws;                    // 32 MB
  __hip_bfloat16* w1t = (__hip_bfloat16*)(ws + (32ull << 20));  // 64 MB
  __hip_bfloat16* w2t = (__hip_bfloat16*)(ws + (96ull << 20));  // 32 MB
  __hip_bfloat16* z   = (__hip_bfloat16*)(ws + (128ull << 20)); // 128 MB
  (void)in_sizes; (void)n_in; (void)out_size; (void)ws_size;

  ln_kernel<<<kTokens, 256, 0, stream>>>(x, gamma, beta, yb);
  cvt_tr<true ><<<dim3(kN1 / 64, kHid / 64), 256, 0, stream>>>(W1, w1t, kHid, kN1);
  cvt_tr<false><<<dim3(kHid / 64, kInter / 64), 256, 0, stream>>>(W2, w2t, kInter, kHid);
  // GEMM1: M=8192, N=16384, K=2048 -> grid 64*32 = 2048 (NXT=64 -> log 6)
  gemm8p<1, 6><<<dim3((kN1 / 256) * (kTokens / 256)), 512, 0, stream>>>(
      yb, w1t, (void*)z, kTokens, kN1, kHid);
  // GEMM2: M=8192, N=2048, K=8192 -> grid 8*32 = 256 (NXT=8 -> log 3)
  gemm8p<0, 3><<<dim3((kHid / 256) * (kTokens / 256)), 512, 0, stream>>>(
      z, w2t, (void*)out, kTokens, kHid, kInter);
}

// Round 7
// 1038.051 us; speedup vs baseline: 1.0326x; 1.0326x over previous
//
#include <hip/hip_runtime.h>
#include <hip/hip_bf16.h>
#include <stdint.h>

typedef __attribute__((ext_vector_type(8))) __bf16 bf16x8;
typedef __attribute__((ext_vector_type(4))) float f32x4;

static constexpr int kTokens = 8192;   // B*S = 4*2048
static constexpr int kHid    = 2048;   // H
static constexpr int kInter  = 8192;   // I
static constexpr int kN1     = 16384;  // 2*I, branch-interleaved in 16-col groups

// ---------------- async global->LDS 16B copy (global_load_lds_dwordx4) ----
__device__ __forceinline__ void async16(const void* g, void* l) {
  using gp = const __attribute__((address_space(1))) unsigned int*;
  using lp = __attribute__((address_space(3))) unsigned int*;
  __builtin_amdgcn_global_load_lds((gp)(uintptr_t)g,
                                   (lp)(unsigned int)(uintptr_t)l, 16, 0, 0);
}

// ---------------- LayerNorm (f32 in) -> bf16 y --------------------------
__global__ __launch_bounds__(256) void ln_kernel(
    const float* __restrict__ x, const float* __restrict__ gamma,
    const float* __restrict__ beta, __hip_bfloat16* __restrict__ y) {
  const int t = threadIdx.x;
  const size_t row = blockIdx.x;
  const float* xr = x + row * kHid;
  float4 v0 = ((const float4*)xr)[2 * t];
  float4 v1 = ((const float4*)xr)[2 * t + 1];
  float s  = v0.x + v0.y + v0.z + v0.w + v1.x + v1.y + v1.z + v1.w;
  float s2 = v0.x*v0.x + v0.y*v0.y + v0.z*v0.z + v0.w*v0.w
           + v1.x*v1.x + v1.y*v1.y + v1.z*v1.z + v1.w*v1.w;
#pragma unroll
  for (int off = 1; off < 64; off <<= 1) {
    s  += __shfl_xor(s, off, 64);
    s2 += __shfl_xor(s2, off, 64);
  }
  __shared__ float red[8];
  const int w = t >> 6;
  if ((t & 63) == 0) { red[w] = s; red[4 + w] = s2; }
  __syncthreads();
  s  = red[0] + red[1] + red[2] + red[3];
  s2 = red[4] + red[5] + red[6] + red[7];
  const float mu = s * (1.0f / kHid);
  const float rs = rsqrtf(s2 * (1.0f / kHid) - mu * mu + 1e-6f);
  float4 g0 = ((const float4*)gamma)[2 * t], g1 = ((const float4*)gamma)[2 * t + 1];
  float4 b0 = ((const float4*)beta)[2 * t],  b1 = ((const float4*)beta)[2 * t + 1];
  union { __hip_bfloat16 h[8]; uint4 u; } pk;
  pk.h[0] = __float2bfloat16((v0.x - mu) * rs * g0.x + b0.x);
  pk.h[1] = __float2bfloat16((v0.y - mu) * rs * g0.y + b0.y);
  pk.h[2] = __float2bfloat16((v0.z - mu) * rs * g0.z + b0.z);
  pk.h[3] = __float2bfloat16((v0.w - mu) * rs * g0.w + b0.w);
  pk.h[4] = __float2bfloat16((v1.x - mu) * rs * g1.x + b1.x);
  pk.h[5] = __float2bfloat16((v1.y - mu) * rs * g1.y + b1.y);
  pk.h[6] = __float2bfloat16((v1.z - mu) * rs * g1.z + b1.z);
  pk.h[7] = __float2bfloat16((v1.w - mu) * rs * g1.w + b1.w);
  ((uint4*)(y + row * kHid))[t] = pk.u;
}

// ---------------- f32 (K x Ncols) -> bf16 transposed (N x K) -------------
template <bool INTERLEAVE>
__global__ __launch_bounds__(256) void cvt_tr(
    const float* __restrict__ src, __hip_bfloat16* __restrict__ dst,
    int K, int N) {
  __shared__ float tile[64][65];
  const int nb = blockIdx.x * 64;
  const int kb = blockIdx.y * 64;
  const int t = threadIdx.x;
#pragma unroll
  for (int it = 0; it < 16; ++it) {
    int p = t + it * 256;
    int lk = p >> 6, ln = p & 63;
    int n = nb + ln;
    int col = INTERLEAVE ? ((((n >> 4) & 1) << 13) + (((n >> 5) << 4) | (n & 15)))
                         : n;
    tile[lk][ln] = src[(size_t)(kb + lk) * N + col];
  }
  __syncthreads();
#pragma unroll
  for (int it = 0; it < 16; ++it) {
    int p = t + it * 256;
    int ln = p >> 6, lk = p & 63;
    dst[(size_t)(nb + ln) * K + kb + lk] = __float2bfloat16(tile[lk][ln]);
  }
}

// ---------------- 256x256 8-phase bf16 GEMM  C = A(MxK) * B^T(NxK) -------
// R2 schedule (session best, 975us total; 16x16x32 MFMA, 0 bank conflicts):
// BK=64, 8 waves (2Mx4N), 512 thr, 2x64KB LDS dbuf in 4 half-tile slots
// + 8KB dummy sink. Counted vmcnt(4) at phases 4/8 only. XOR chunk swizzle
// (chunk ^= row&7): linear LDS dest, inverse-swizzled global source,
// swizzled ds_read. ds_read groups 8/4/8/4 (bfN0 early-issued inside the
// prior PHASE_MID_VM region). Staging ledger (iter i):
//   ph1:(2i+1).A0 ph2:(2i+1).A1 ph3:(2i+2).B0 ph4:(2i+2).B1+VM
//   ph5:(2i+2).A0 ph6:(2i+2).A1 ph7:(2i+3).B0 ph8:(2i+3).B1+VM
// Tail tiles stage dummies so vmcnt counts never change.
//
// R6 = R5 theory with the R5 bug fixed: R5 wrote gr0 with wm*64 (correct
// is wm*128 — each of the 2 M-waves owns a 128-row half; m89 layout) so
// rows 192..255 of every tile were never written. Nontemporal epilogue
// stores retained: FETCH_SIZE 1.08GB vs ~96MB distinct input = 11x HBM
// over-fetch at 26% BW -> the 128MB z / 64MB out write-streams evict the
// weight panels from L2/L3 between reuses; outputs gain nothing from
// caching (z consumed a kernel later, out never re-read).
#define SLOT_A(b, h) ((b) * 65536 + (h) * 16384)
#define SLOT_B(b, h) ((b) * 65536 + 32768 + (h) * 16384)
#define SLOT_DUMMY 131072

template <int EPI, int NXTLOG>
__global__ __launch_bounds__(512, 2) void gemm8p(
    const __hip_bfloat16* __restrict__ A, const __hip_bfloat16* __restrict__ B,
    void* __restrict__ Cout, int M, int N, int K) {
  __shared__ __align__(16) char smem[139264];
  char* const sm = (char*)smem;

  const int t = threadIdx.x;
  const int lane = t & 63;
  const int wave = t >> 6;
  const int wm = wave >> 2;  // 0..1 (M waves, 128 rows each)
  const int wn = wave & 3;   // 0..3 (N waves, 64 cols each)

  // XCD-aware bijective swizzle (caller guarantees grid % 8 == 0)
  const int nwg = (int)gridDim.x;
  const int wg = ((int)blockIdx.x & 7) * (nwg >> 3) + ((int)blockIdx.x >> 3);
  const int bx = wg & ((1 << NXTLOG) - 1);
  const int by = wg >> NXTLOG;
  const size_t m0 = (size_t)by * 256;
  const size_t n0 = (size_t)bx * 256;

  // staging lane constants: thread t writes linear LDS bytes t*16 (+8192);
  // row = t>>3 (+64 for 2nd load), stored chunk = t&7, source chunk XOR'd.
  const int srow = t >> 3;
  const int scsrc = (t & 7) ^ (srow & 7);
  const __hip_bfloat16* const gA = A + (m0 + srow) * K + scsrc * 8;
  const __hip_bfloat16* const gB = B + (n0 + srow) * K + scsrc * 8;
  const size_t K64  = (size_t)64 * K;
  const size_t K128 = (size_t)128 * K;
  const int t16 = t * 16;
  char* const dm = sm + SLOT_DUMMY + t16;

  // fragment-read lane constants (row&7 == col&7 for all frag rows)
  const int col = lane & 15, q = lane >> 4;
  const int cs0 = (q ^ (col & 7)) * 16;        // kk=0 stored chunk
  const int cs1 = ((4 + q) ^ (col & 7)) * 16;  // kk=1
  const int aO0 = wm * 16384 + col * 128 + cs0;
  const int aO1 = wm * 16384 + col * 128 + cs1;
  const int bO0 = 32768 + (wn >> 1) * 16384 + ((wn & 1) * 64 + col) * 128 + cs0;
  const int bO1 = 32768 + (wn >> 1) * 16384 + ((wn & 1) * 64 + col) * 128 + cs1;

  f32x4 acc[8][4] = {};
  bf16x8 af[4][2], bf[4][2];

  const int NT = K >> 6;  // 64-wide K tiles (even for both GEMMs)
  const int L  = NT >> 1; // 2 tiles per iteration

#define STG_A(tile, h, buf)                                           \
  do {                                                                \
    const __hip_bfloat16* _s = gA + (size_t)(tile) * 64 + (h) * K128; \
    char* _d = sm + SLOT_A(buf, h) + t16;                             \
    async16(_s, _d);                                                  \
    async16(_s + K64, _d + 8192);                                     \
  } while (0)
#define STG_B(tile, h, buf)                                           \
  do {                                                                \
    const __hip_bfloat16* _s = gB + (size_t)(tile) * 64 + (h) * K128; \
    char* _d = sm + SLOT_B(buf, h) + t16;                             \
    async16(_s, _d);                                                  \
    async16(_s + K64, _d + 8192);                                     \
  } while (0)
#define STG_A_G(tile, h, buf)                  \
  do {                                         \
    if ((tile) < NT) { STG_A(tile, h, buf); }  \
    else { async16(A, dm); async16(A, dm); }   \
  } while (0)
#define STG_B_G(tile, h, buf)                  \
  do {                                         \
    if ((tile) < NT) { STG_B(tile, h, buf); }  \
    else { async16(A, dm); async16(A, dm); }   \
  } while (0)

#define LOAD_A(buf, mh)                                                        \
  { _Pragma("unroll") for (int ii = 0; ii < 4; ++ii) {                         \
      af[ii][0] = *(const bf16x8*)(sm + (buf)*65536 + aO0 + (mh)*8192 + ii*2048); \
      af[ii][1] = *(const bf16x8*)(sm + (buf)*65536 + aO1 + (mh)*8192 + ii*2048); \
  } }
#define LOAD_B(buf, nh)                                                        \
  { _Pragma("unroll") for (int jj = 0; jj < 2; ++jj) {                         \
      bf[(nh)*2 + jj][0] = *(const bf16x8*)(sm + (buf)*65536 + bO0 + ((nh)*2 + jj)*2048); \
      bf[(nh)*2 + jj][1] = *(const bf16x8*)(sm + (buf)*65536 + bO1 + ((nh)*2 + jj)*2048); \
  } }

#define MFMA_QUAD(mh, nh)                                                     \
  { _Pragma("unroll") for (int kk = 0; kk < 2; ++kk)                          \
    _Pragma("unroll") for (int ii = 0; ii < 4; ++ii)                          \
    _Pragma("unroll") for (int jj = 0; jj < 2; ++jj)                          \
      acc[(mh)*4 + ii][(nh)*2 + jj] = __builtin_amdgcn_mfma_f32_16x16x32_bf16( \
          af[ii][kk], bf[(nh)*2 + jj][kk], acc[(mh)*4 + ii][(nh)*2 + jj], 0, 0, 0); }

#define PHASE_MID()                                  \
  __builtin_amdgcn_s_barrier();                      \
  asm volatile("s_waitcnt lgkmcnt(0)" ::: "memory"); \
  __builtin_amdgcn_s_setprio(1)
#define PHASE_MID_VM()                               \
  asm volatile("s_waitcnt vmcnt(4)" ::: "memory");   \
  __builtin_amdgcn_s_barrier();                      \
  asm volatile("s_waitcnt lgkmcnt(0)" ::: "memory"); \
  __builtin_amdgcn_s_setprio(1)
#define PHASE_END()                                  \
  __builtin_amdgcn_s_setprio(0);                     \
  __builtin_amdgcn_s_barrier()

  // prologue: tile0 {A0,A1,B0,B1} + tile1 {B0,B1}; wait leaves tile1.B in
  // flight. Then pre-issue bfN0(tile0) (loop-carried: ph8 feeds ph1).
  STG_A(0, 0, 0);
  STG_A(0, 1, 0);
  STG_B(0, 0, 0);
  STG_B(0, 1, 0);
  STG_B(1, 0, 1);
  STG_B(1, 1, 1);
  asm volatile("s_waitcnt vmcnt(4)" ::: "memory");
  __builtin_amdgcn_s_barrier();
  LOAD_B(0, 0)

#pragma unroll 1
  for (int i = 0; i < L; ++i) {
    const int t1 = 2 * i + 1, t2 = 2 * i + 2, t3 = 2 * i + 3;
    // ph1: tile 2i (buf0) quad(0,0) — bf[0..1] already in flight from ph8
    LOAD_A(0, 0)
    STG_A(t1, 0, 1);
    PHASE_MID(); MFMA_QUAD(0, 0) PHASE_END();
    // ph2: quad(0,1)
    LOAD_B(0, 1)
    STG_A(t1, 1, 1);
    PHASE_MID(); MFMA_QUAD(0, 1) PHASE_END();
    // ph3: quad(1,0)
    LOAD_A(0, 1)
    STG_B_G(t2, 0, 0);
    PHASE_MID(); MFMA_QUAD(1, 0) PHASE_END();
    // ph4: quad(1,1); vmcnt(4) -> tile 2i+1 resident; early-issue bfN0(buf1)
    // inside MFMA region (reads fill bf[0..1], MFMA uses bf[2..3])
    STG_B_G(t2, 1, 0);
    PHASE_MID_VM();
    LOAD_B(1, 0)
    MFMA_QUAD(1, 1) PHASE_END();
    // ph5: tile 2i+1 (buf1) quad(0,0)
    LOAD_A(1, 0)
    STG_A_G(t2, 0, 0);
    PHASE_MID(); MFMA_QUAD(0, 0) PHASE_END();
    // ph6: quad(0,1)
    LOAD_B(1, 1)
    STG_A_G(t2, 1, 0);
    PHASE_MID(); MFMA_QUAD(0, 1) PHASE_END();
    // ph7: quad(1,0)
    LOAD_A(1, 1)
    STG_B_G(t3, 0, 1);
    PHASE_MID(); MFMA_QUAD(1, 0) PHASE_END();
    // ph8: quad(1,1); vmcnt(4) -> tile 2i+2 resident; early-issue bfN0(buf0)
    // for next iteration's ph1 (harmless garbage read on final iteration)
    STG_B_G(t3, 1, 1);
    PHASE_MID_VM();
    LOAD_B(0, 0)
    MFMA_QUAD(1, 1) PHASE_END();
  }
  asm volatile("s_waitcnt vmcnt(0)" ::: "memory");  // drain before LDS dealloc

  // C/D layout: col = lane&15, row = (lane>>4)*4 + reg   [m89-verified]
  // Each M-wave owns a 128-row half: gr0 = m0 + wm*128 + q*4  (R5 bug was
  // wm*64). Nontemporal stores keep the output stream out of L2/L3.
  const int gr0 = (int)m0 + wm * 128 + q * 4;
  if (EPI == 0) {
    float* Cf = (float*)Cout;
    const int gc0 = (int)n0 + wn * 64 + col;
#pragma unroll
    for (int mi = 0; mi < 8; ++mi)
#pragma unroll
      for (int j = 0; j < 4; ++j) {
        size_t base = (size_t)(gr0 + mi * 16) * N + gc0 + j * 16;
#pragma unroll
        for (int r = 0; r < 4; ++r)
          __builtin_nontemporal_store(acc[mi][j][r], &Cf[base + (size_t)r * N]);
      }
  } else {
    __hip_bfloat16* Z = (__hip_bfloat16*)Cout;
    const int ldz = N >> 1;
    const size_t ib0 = (n0 >> 1) + wn * 32 + col;
#pragma unroll
    for (int mi = 0; mi < 8; ++mi)
#pragma unroll
      for (int tp = 0; tp < 2; ++tp) {
        const f32x4 gg = acc[mi][2 * tp];      // gate (a=0) 16-col tile
        const f32x4 ll = acc[mi][2 * tp + 1];  // linear (a=1) 16-col tile
        size_t base = (size_t)(gr0 + mi * 16) * ldz + ib0 + tp * 16;
#pragma unroll
        for (int r = 0; r < 4; ++r) {
          // gelu_tanh(x) = x * sigmoid(2u), u = 0.79788456*(x + 0.044715 x^3)
          float xv = gg[r];
          float u = 0.7978845608028654f * xv * (1.0f + 0.044715f * xv * xv);
          float sg = __builtin_amdgcn_rcpf(1.0f + __expf(-2.0f * u));
          union { __hip_bfloat16 h; unsigned short us; } cv;
          cv.h = __float2bfloat16(xv * sg * ll[r]);
          __builtin_nontemporal_store(
              cv.us, (unsigned short*)Z + base + (size_t)r * ldz);
        }
      }
  }
}

extern "C" void kernel_launch(void* const* d_in, const int* in_sizes, int n_in,
                              void* d_out, int out_size, void* d_ws, size_t ws_size,
                              hipStream_t stream) {
  const float* x     = (const float*)d_in[0];
  const float* gamma = (const float*)d_in[1];
  const float* beta  = (const float*)d_in[2];
  const float* W1    = (const float*)d_in[3];  // [H, 2, I] f32
  const float* W2    = (const float*)d_in[4];  // [I, H] f32
  float* out = (float*)d_out;

  char* ws = (char*)d_ws;
  __hip_bfloat16* yb  = (__hip_bfloat16*)ws;                    // 32 MB
  __hip_bfloat16* w1t = (__hip_bfloat16*)(ws + (32ull << 20));  // 64 MB
  __hip_bfloat16* w2t = (__hip_bfloat16*)(ws + (96ull << 20));  // 32 MB
  __hip_bfloat16* z   = (__hip_bfloat16*)(ws + (128ull << 20)); // 128 MB
  (void)in_sizes; (void)n_in; (void)out_size; (void)ws_size;

  ln_kernel<<<kTokens, 256, 0, stream>>>(x, gamma, beta, yb);
  cvt_tr<true ><<<dim3(kN1 / 64, kHid / 64), 256, 0, stream>>>(W1, w1t, kHid, kN1);
  cvt_tr<false><<<dim3(kHid / 64, kInter / 64), 256, 0, stream>>>(W2, w2t, kInter, kHid);
  // GEMM1: M=8192, N=16384, K=2048 -> grid 64*32 = 2048 (NXT=64 -> log 6)
  gemm8p<1, 6><<<dim3((kN1 / 256) * (kTokens / 256)), 512, 0, stream>>>(
      yb, w1t, (void*)z, kTokens, kN1, kHid);
  // GEMM2: M=8192, N=2048, K=8192 -> grid 8*32 = 256 (NXT=8 -> log 3)
  gemm8p<0, 3><<<dim3((kHid / 256) * (kTokens / 256)), 512, 0, stream>>>(
      z, w2t, (void*)out, kTokens, kHid, kInter);
}